// Round 1
// baseline (128.579 us; speedup 1.0000x reference)
//
#include <hip/hip_runtime.h>
#include <hip/hip_cooperative_groups.h>
#include <stdint.h>

// FP4 quant-dequant, faithful to the JAX reference in float32 arithmetic.
// v3: single cooperative kernel. x is held in registers across grid.sync();
// eliminates k_reduce, the scales[] round-trip, the x re-read, and 2 launches.
// 4-lane groups own each 64-block (16 contiguous elems/lane, 64B lane stride);
// top-5 merged across the group with 2 shfl_xor steps. Exact max/min insertion
// makes the top-5 order-independent -> bit-identical s/ds/output vs v2.
// Falls back to the verified v2 3-kernel path if coop occupancy/launch fails.

#define BLK 64
#define WG 256
#define COOP_WGS 1024   // 4 blocks/CU x 256 CUs; __launch_bounds__(WG,4) caps VGPR<=128
#define FLT_BIG 3.402823466e+38f

namespace cg = cooperative_groups;

// Branchless insert of `a` into descending-sorted top-5 register array.
__device__ __forceinline__ void ins5(float (&t)[5], float a) {
#pragma unroll
    for (int k = 0; k < 4; ++k) {
        float m = fmaxf(t[k], a);
        a = fminf(t[k], a);
        t[k] = m;
    }
    t[4] = fmaxf(t[4], a);
}

// JAX f32 quantile: q = 0.95f*63.0f; result = v59*lw + v60*hw
__device__ __forceinline__ float quantile5(const float (&A)[5]) {
    const float qs = 0.95f * 63.0f;      // 59.849998474121094f
    const float hw = qs - 59.0f;
    const float lw = 60.0f - qs;
    // A[3] = 4th largest = sorted v[60]; A[4] = 5th largest = v[59]
    float s = __fadd_rn(__fmul_rn(A[4], lw), __fmul_rn(A[3], hw));
    return fmaxf(s, 1e-8f);
}

// Nearest FP4 level via boundary ladder (exact dyadics; ties match argmin).
__device__ __forceinline__ float qlevel(float xn) {
    float bv = -3.0f;
    bv += (xn > -2.5f)   ? 1.0f  : 0.0f;
    bv += (xn > -1.75f)  ? 0.5f  : 0.0f;
    bv += (xn > -1.25f)  ? 0.5f  : 0.0f;
    bv += (xn > -0.875f) ? 0.25f : 0.0f;
    bv += (xn > -0.375f) ? 0.75f : 0.0f;
    bv += (xn > 0.375f)  ? 0.75f : 0.0f;
    bv += (xn > 0.875f)  ? 0.25f : 0.0f;
    bv += (xn > 1.25f)   ? 0.5f  : 0.0f;
    bv += (xn > 1.75f)   ? 0.5f  : 0.0f;
    bv += (xn > 2.5f)    ? 1.0f  : 0.0f;
    return bv;
}

// ---------------- Fused cooperative kernel ----------------
// Task j covers elements [16j, 16j+16). Thread t does tasks j = c*T + t,
// c = 0..3 (T = total threads, T%4==0). Tasks 4b..4b+3 -> aligned 4-lane
// group in one wave -> block b is owned by that group.
__global__ __launch_bounds__(WG, 4) void k_fused(const float* __restrict__ x,
                                                 int n,
                                                 float* __restrict__ out,
                                                 float* __restrict__ partMin,
                                                 float* __restrict__ partMax) {
    const int T = (int)gridDim.x * WG;
    const int t = (int)blockIdx.x * WG + (int)threadIdx.x;

    float4 d[16];   // 4 chunks x 16 floats, all compile-time indexed (no scratch)
    float  sC[4];

    // ---------- Phase 1: load + per-block scale ----------
#pragma unroll
    for (int c = 0; c < 4; ++c) {
        const int base = (c * T + t) << 4;   // element index; <= 2^24 in coop path
        if (base + 16 <= n) {
            const float4* x4 = reinterpret_cast<const float4*>(x + base);
#pragma unroll
            for (int q = 0; q < 4; ++q) d[c * 4 + q] = x4[q];
        } else {
#pragma unroll
            for (int q = 0; q < 4; ++q) {
                const int i0 = base + q * 4;
                float e0 = (i0 + 0 < n) ? x[i0 + 0] : 0.0f;  // reference zero-pads
                float e1 = (i0 + 1 < n) ? x[i0 + 1] : 0.0f;
                float e2 = (i0 + 2 < n) ? x[i0 + 2] : 0.0f;
                float e3 = (i0 + 3 < n) ? x[i0 + 3] : 0.0f;
                d[c * 4 + q] = make_float4(e0, e1, e2, e3);
            }
        }
        // Two insertion chains for ILP over this lane's 16 |x|; abs>=0 so 0-init ok.
        float A[5] = {0.f, 0.f, 0.f, 0.f, 0.f};
        float B[5] = {0.f, 0.f, 0.f, 0.f, 0.f};
#pragma unroll
        for (int q = 0; q < 4; q += 2) {
            ins5(A, fabsf(d[c * 4 + q].x));     ins5(B, fabsf(d[c * 4 + q + 1].x));
            ins5(A, fabsf(d[c * 4 + q].y));     ins5(B, fabsf(d[c * 4 + q + 1].y));
            ins5(A, fabsf(d[c * 4 + q].z));     ins5(B, fabsf(d[c * 4 + q + 1].z));
            ins5(A, fabsf(d[c * 4 + q].w));     ins5(B, fabsf(d[c * 4 + q + 1].w));
        }
#pragma unroll
        for (int k = 0; k < 5; ++k) ins5(A, B[k]);
        // Merge top-5 lists across the 4-lane group (block = 64 elements).
#pragma unroll
        for (int m = 1; m <= 2; m <<= 1) {
            float o0 = __shfl_xor(A[0], m, 64);
            float o1 = __shfl_xor(A[1], m, 64);
            float o2 = __shfl_xor(A[2], m, 64);
            float o3 = __shfl_xor(A[3], m, 64);
            float o4 = __shfl_xor(A[4], m, 64);
            ins5(A, o0); ins5(A, o1); ins5(A, o2); ins5(A, o3); ins5(A, o4);
        }
        sC[c] = quantile5(A);
    }

    // ---------- Per-WG min/max partials over valid blocks ----------
    float mn = FLT_BIG, mx = 0.0f;
#pragma unroll
    for (int c = 0; c < 4; ++c) {
        const int b = (c * T + t) >> 2;      // block id of this chunk
        if (b * BLK < n) { mn = fminf(mn, sC[c]); mx = fmaxf(mx, sC[c]); }
    }
#pragma unroll
    for (int off = 32; off > 0; off >>= 1) {
        mn = fminf(mn, __shfl_xor(mn, off, 64));
        mx = fmaxf(mx, __shfl_xor(mx, off, 64));
    }
    __shared__ float smn[4], smx[4];
    const int lane = threadIdx.x & 63, w = threadIdx.x >> 6;
    if (lane == 0) { smn[w] = mn; smx[w] = mx; }
    __syncthreads();
    if (threadIdx.x == 0) {
        float fmn = smn[0], fmx = smx[0];
#pragma unroll
        for (int i = 1; i < 4; ++i) { fmn = fminf(fmn, smn[i]); fmx = fmaxf(fmx, smx[i]); }
        partMin[blockIdx.x] = fmn;
        partMax[blockIdx.x] = fmx;
    }

    cg::this_grid().sync();

    // ---------- Redundant per-WG reduce of gridDim partials (L2-hot) ----------
    float gmn = FLT_BIG, gmx = 0.0f;
    for (int i = threadIdx.x; i < (int)gridDim.x; i += WG) {
        gmn = fminf(gmn, partMin[i]);
        gmx = fmaxf(gmx, partMax[i]);
    }
#pragma unroll
    for (int off = 32; off > 0; off >>= 1) {
        gmn = fminf(gmn, __shfl_xor(gmn, off, 64));
        gmx = fmaxf(gmx, __shfl_xor(gmx, off, 64));
    }
    if (lane == 0) { smn[w] = gmn; smx[w] = gmx; }
    __syncthreads();
    const float smin = fminf(fminf(smn[0], smn[1]), fminf(smn[2], smn[3]));
    const float smax = fmaxf(fmaxf(smx[0], smx[1]), fmaxf(smx[2], smx[3]));

    // ---------- Phase 2: quantize straight from registers ----------
    const bool  cond = (smax > smin);
    const float ss   = cond ? __fdiv_rn(__fsub_rn(smax, smin), 255.0f) : 1.0f;
#pragma unroll
    for (int c = 0; c < 4; ++c) {
        const int base = (c * T + t) << 4;
        if (base >= n) continue;
        const float s = sC[c];
        float ds;
        if (cond) {
            float q = rintf(__fdiv_rn(__fsub_rn(s, smin), ss));   // round half-even
            q = fminf(fmaxf(q, 0.0f), 255.0f);                    // clip AFTER round
            ds = __fmul_rn(q, ss);
        } else {
            ds = 0.0f;   // q=0, scale_scale=1 -> deq 0
        }
        if (base + 16 <= n) {
            float4* o4 = reinterpret_cast<float4*>(out + base);
#pragma unroll
            for (int q4 = 0; q4 < 4; ++q4) {
                const float4 xv = d[c * 4 + q4];
                float4 ov;
                ov.x = __fmul_rn(qlevel(__fdiv_rn(xv.x, s)), ds);
                ov.y = __fmul_rn(qlevel(__fdiv_rn(xv.y, s)), ds);
                ov.z = __fmul_rn(qlevel(__fdiv_rn(xv.z, s)), ds);
                ov.w = __fmul_rn(qlevel(__fdiv_rn(xv.w, s)), ds);
                o4[q4] = ov;
            }
        } else {
#pragma unroll
            for (int q4 = 0; q4 < 4; ++q4) {
                const float4 xv = d[c * 4 + q4];
                const int i0 = base + q4 * 4;
                if (i0 + 0 < n) out[i0 + 0] = __fmul_rn(qlevel(__fdiv_rn(xv.x, s)), ds);
                if (i0 + 1 < n) out[i0 + 1] = __fmul_rn(qlevel(__fdiv_rn(xv.y, s)), ds);
                if (i0 + 2 < n) out[i0 + 2] = __fmul_rn(qlevel(__fdiv_rn(xv.z, s)), ds);
                if (i0 + 3 < n) out[i0 + 3] = __fmul_rn(qlevel(__fdiv_rn(xv.w, s)), ds);
            }
        }
    }
}

// ---------------- v2 fallback path (verified) ----------------
__global__ __launch_bounds__(WG) void k_scales(const float* __restrict__ x,
                                               int n, int nblocks,
                                               float* __restrict__ scales,
                                               float* __restrict__ partMin,
                                               float* __restrict__ partMax) {
    const int b = blockIdx.x * WG + threadIdx.x;
    const bool valid = (b < nblocks);

    float s = 0.0f;
    if (valid) {
        float4 v[16];
        const int base = b * BLK;
        if (base + BLK <= n) {
            const float4* x4 = reinterpret_cast<const float4*>(x + base);
#pragma unroll
            for (int j = 0; j < 16; ++j) v[j] = x4[j];
        } else {
            for (int j = 0; j < 16; ++j) {
                float tmp[4];
                for (int k = 0; k < 4; ++k) {
                    int idx = base + j * 4 + k;
                    tmp[k] = (idx < n) ? x[idx] : 0.0f;
                }
                v[j] = make_float4(tmp[0], tmp[1], tmp[2], tmp[3]);
            }
        }
        float A[5] = {0.f, 0.f, 0.f, 0.f, 0.f};
        float B[5] = {0.f, 0.f, 0.f, 0.f, 0.f};
#pragma unroll
        for (int j = 0; j < 16; j += 2) {
            ins5(A, fabsf(v[j].x));     ins5(B, fabsf(v[j + 1].x));
            ins5(A, fabsf(v[j].y));     ins5(B, fabsf(v[j + 1].y));
            ins5(A, fabsf(v[j].z));     ins5(B, fabsf(v[j + 1].z));
            ins5(A, fabsf(v[j].w));     ins5(B, fabsf(v[j + 1].w));
        }
#pragma unroll
        for (int k = 0; k < 5; ++k) ins5(A, B[k]);
        s = quantile5(A);
        scales[b] = s;
    }

    float mn = valid ? s : FLT_BIG;
    float mx = valid ? s : 0.0f;
#pragma unroll
    for (int off = 32; off > 0; off >>= 1) {
        mn = fminf(mn, __shfl_xor(mn, off, 64));
        mx = fmaxf(mx, __shfl_xor(mx, off, 64));
    }
    __shared__ float smn[4], smx[4];
    const int lane = threadIdx.x & 63, w = threadIdx.x >> 6;
    if (lane == 0) { smn[w] = mn; smx[w] = mx; }
    __syncthreads();
    if (threadIdx.x == 0) {
        float fmn = smn[0], fmx = smx[0];
#pragma unroll
        for (int i = 1; i < 4; ++i) { fmn = fminf(fmn, smn[i]); fmx = fmaxf(fmx, smx[i]); }
        partMin[blockIdx.x] = fmn;
        partMax[blockIdx.x] = fmx;
    }
}

__global__ __launch_bounds__(WG) void k_reduce(const float* __restrict__ partMin,
                                               const float* __restrict__ partMax,
                                               int nparts,
                                               float* __restrict__ hdr) {
    float mn = FLT_BIG, mx = 0.0f;
    for (int i = threadIdx.x; i < nparts; i += WG) {
        mn = fminf(mn, partMin[i]);
        mx = fmaxf(mx, partMax[i]);
    }
#pragma unroll
    for (int off = 32; off > 0; off >>= 1) {
        mn = fminf(mn, __shfl_xor(mn, off, 64));
        mx = fmaxf(mx, __shfl_xor(mx, off, 64));
    }
    __shared__ float smn[4], smx[4];
    int lane = threadIdx.x & 63, w = threadIdx.x >> 6;
    if (lane == 0) { smn[w] = mn; smx[w] = mx; }
    __syncthreads();
    if (threadIdx.x == 0) {
        float fmn = smn[0], fmx = smx[0];
#pragma unroll
        for (int i = 1; i < 4; ++i) { fmn = fminf(fmn, smn[i]); fmx = fmaxf(fmx, smx[i]); }
        hdr[0] = fmn; hdr[1] = fmx;
    }
}

__global__ __launch_bounds__(WG) void k_quant(const float* __restrict__ x,
                                              const float* __restrict__ scales,
                                              const float* __restrict__ hdr,
                                              int n,
                                              float* __restrict__ out) {
    const int t = blockIdx.x * WG + threadIdx.x;
    const int i = t * 4;
    if (i >= n) return;

    const float smin = hdr[0], smax = hdr[1];
    const int b = i >> 6;
    const float s = scales[b];

    float ds;
    if (smax > smin) {
        const float ss = __fdiv_rn(__fsub_rn(smax, smin), 255.0f);
        float q = rintf(__fdiv_rn(__fsub_rn(s, smin), ss));
        q = fminf(fmaxf(q, 0.0f), 255.0f);
        ds = __fmul_rn(q, ss);
    } else {
        ds = 0.0f;
    }

    if (i + 3 < n) {
        const float4 xv = *reinterpret_cast<const float4*>(x + i);
        float4 ov;
        ov.x = __fmul_rn(qlevel(__fdiv_rn(xv.x, s)), ds);
        ov.y = __fmul_rn(qlevel(__fdiv_rn(xv.y, s)), ds);
        ov.z = __fmul_rn(qlevel(__fdiv_rn(xv.z, s)), ds);
        ov.w = __fmul_rn(qlevel(__fdiv_rn(xv.w, s)), ds);
        *reinterpret_cast<float4*>(out + i) = ov;
    } else {
        for (int j = 0; j < 4 && i + j < n; ++j)
            out[i + j] = __fmul_rn(qlevel(__fdiv_rn(x[i + j], s)), ds);
    }
}

extern "C" void kernel_launch(void* const* d_in, const int* in_sizes, int n_in,
                              void* d_out, int out_size, void* d_ws, size_t ws_size,
                              hipStream_t stream) {
    const float* x = (const float*)d_in[0];
    float* out = (float*)d_out;
    const int n = in_sizes[0];
    float* ws = (float*)d_ws;

    // ---- cooperative fused path (n must fit 4 chunks x 16 elems/thread) ----
    const bool fits = ((long long)n <= (long long)COOP_WGS * WG * 64);
    if (fits) {
        static int coopOK = -1;   // host-only queries, graph-capture safe
        if (coopOK < 0) {
            int nb = 0;
            hipError_t e1 = hipOccupancyMaxActiveBlocksPerMultiprocessor(&nb, k_fused, WG, 0);
            int dev = 0;
            (void)hipGetDevice(&dev);
            hipDeviceProp_t prop;
            hipError_t e2 = hipGetDeviceProperties(&prop, dev);
            coopOK = (e1 == hipSuccess && e2 == hipSuccess &&
                      prop.cooperativeLaunch &&
                      (long long)nb * prop.multiProcessorCount >= COOP_WGS) ? 1 : 0;
        }
        if (coopOK == 1) {
            float* partMin = ws;               // COOP_WGS floats
            float* partMax = ws + COOP_WGS;    // COOP_WGS floats
            const float* xa = x;
            int na = n;
            float* oa = out;
            void* args[] = {(void*)&xa, (void*)&na, (void*)&oa,
                            (void*)&partMin, (void*)&partMax};
            hipError_t err = hipLaunchCooperativeKernel(k_fused, dim3(COOP_WGS), dim3(WG),
                                                        args, 0u, stream);
            if (err == hipSuccess) return;
            (void)hipGetLastError();   // clear and fall through to v2 path
        }
    }

    // ---- v2 fallback: 3-kernel path ----
    const int nblocks = (n + BLK - 1) / BLK;
    const int nwgScales = (nblocks + WG - 1) / WG;

    float* scales  = ws;
    float* partMin = ws + nblocks;
    float* partMax = partMin + nwgScales;
    float* hdr     = partMax + nwgScales;

    k_scales<<<nwgScales, WG, 0, stream>>>(x, n, nblocks, scales, partMin, partMax);
    k_reduce<<<1, WG, 0, stream>>>(partMin, partMax, nwgScales, hdr);
    k_quant<<<((n + 3) / 4 + WG - 1) / WG, WG, 0, stream>>>(x, scales, hdr, n, out);
}